// Round 4
// baseline (253.822 us; speedup 1.0000x reference)
//
#include <hip/hip_runtime.h>
#include <math.h>

#define KB 16

// Native clang vector type — required for __builtin_nontemporal_store.
typedef float vf4 __attribute__((ext_vector_type(4)));

// Per-element core. Faithful fp32 op order vs reference (__f*_rn blocks FMA
// contraction; rintf == round-half-even == jnp.round). Division by alpha is
// multiply by precomputed 1/alpha — bit-exact for pow2 alpha (bench: 1.0).
// Table holds pv[m] = __fmul_rn(alpha, zval[m]) (same operands/op as the
// reference's final alpha-multiply -> bit-identical; high path alpha*1.0 ==
// alpha exactly). Prior rounds: absmax exactly 0.0.
__device__ __forceinline__ float lcq_core(float xv, float alpha, float rcp_alpha,
                                          const float2* __restrict__ s_gb,
                                          const float* __restrict__ s_pv)
{
    float a   = fabsf(xv);
    float xt  = __fmul_rn(a, rcp_alpha);            // x_tmp = |x|/alpha
    float t16 = __fmul_rn(xt, 16.0f);               // exact pow2 scale
    float jf  = fminf(t16, 15.0f);
    int   j   = (int)jf;                            // searchsorted(dst,·,right)-1
    float2 gb = s_gb[j];                            // ds_read_b64, conflict-free
    float dj  = __fmul_rn(floorf(jf), 0.0625f);     // dst[j] = j/16, exact
    float y   = __fadd_rn(__fmul_rn(gb.x, __fsub_rn(xt, dj)), gb.y);
    float t   = rintf(__fmul_rn(y, 15.0f));         // m = round(y*s), half-even; t>=0
    int   m   = (int)fminf(t, 15.0f);
    float r   = (a < alpha) ? s_pv[m] : alpha;      // flag select, alpha pre-folded
    return copysignf(r, xv);                        // x==0 -> 0 (pv[0]==0)
}

// Structure (R3 theory): R2 counters (VALUBusy 37%, hbm 29%, occ 58%, nothing
// saturated => latency/duty-cycle bound) showed each wave's phase-serial
// load->drain->compute->store left ZERO memory in flight during compute.
// Each block owns 4 contiguous chunks (4096 float4 = 256KB) and software-
// pipelines them depth-1: loads of chunk i+1 in flight while chunk i computes
// (register ping-pong, hand-unrolled, static indexing only — rule #20).
// NT stores (R2 A/B: plain stores cost ~10us); PLAIN loads (R2: LLC served
// half the read traffic -> FETCH_SIZE 65.6GB).
__global__ __launch_bounds__(256) void lcq_kernel(
    const float* __restrict__ x,
    const float* __restrict__ thr,
    const float* __restrict__ theta,
    float* __restrict__ out,
    long long n)
{
    __shared__ float2 s_gb[KB];     // (gamma[j], beta[j])
    __shared__ float  s_pv[KB];     // alpha * expand(m/15)
    __shared__ float  s_scal[2];    // alpha, 1/alpha

    if (threadIdx.x == 0) {
        // softmax(theta), fp32, sequential order (bit-matched all rounds)
        float th[KB];
        float mx = theta[0];
        th[0] = mx;
        #pragma unroll
        for (int i = 1; i < KB; ++i) { th[i] = theta[i]; mx = fmaxf(mx, th[i]); }
        float ex[KB];
        float sum = 0.0f;
        #pragma unroll
        for (int i = 0; i < KB; ++i) { ex[i] = expf(__fsub_rn(th[i], mx)); sum = __fadd_rn(sum, ex[i]); }
        float sm[KB];
        #pragma unroll
        for (int i = 0; i < KB; ++i) sm[i] = __fdiv_rn(ex[i], sum);

        float beta[KB], gamma[KB];
        beta[0] = 0.0f;
        float c = sm[0];
        #pragma unroll
        for (int i = 1; i < KB; ++i) { beta[i] = c; c = __fadd_rn(c, sm[i]); }
        #pragma unroll
        for (int i = 0; i < KB; ++i) gamma[i] = __fmul_rn(sm[i], 16.0f);

        #pragma unroll
        for (int i = 0; i < KB; ++i) s_gb[i] = make_float2(gamma[i], beta[i]);

        float alpha = thr[0];
        s_scal[0] = alpha;
        s_scal[1] = __fdiv_rn(1.0f, alpha);  // exact for pow2 alpha (bench: 1.0)

        // pv[m] = alpha * expand(m/15): searchsorted + inverse affine, then
        // the reference's alpha-multiply pre-folded (same operands -> same bits)
        for (int m = 0; m < KB; ++m) {
            float yq = __fdiv_rn((float)m, 15.0f);
            int iq = 0;
            #pragma unroll
            for (int i = 1; i < KB; ++i) iq += (beta[i] <= yq) ? 1 : 0;
            float zv = __fadd_rn(__fdiv_rn(__fsub_rn(yq, beta[iq]), gamma[iq]),
                                 (float)iq * 0.0625f);
            s_pv[m] = __fmul_rn(alpha, zv);
        }
    }
    __syncthreads();

    const float alpha = s_scal[0];
    const float rcpa  = s_scal[1];

    const long long n4ll = n >> 2;
    const vf4* __restrict__ x4 = (const vf4*)x;
    vf4* __restrict__ o4 = (vf4*)out;

    // block owns float4 indices [b*4096, (b+1)*4096): 4 chunks of 1024
    const size_t blk = (size_t)blockIdx.x * 4096u + threadIdx.x;

// Explicit register names — no token pasting across member access (R3 build
// failure: A##0.x pastes 'a' with pp-number '0.x' -> invalid token).
#define LCQ_LOAD(V0, V1, V2, V3, off) \
    V0 = x4[blk + (off)];        V1 = x4[blk + (off) + 256u]; \
    V2 = x4[blk + (off) + 512u]; V3 = x4[blk + (off) + 768u];

#define LCQ_CS(V0, V1, V2, V3, off) { \
    vf4 r0, r1, r2, r3; \
    r0.x = lcq_core(V0.x, alpha, rcpa, s_gb, s_pv); \
    r0.y = lcq_core(V0.y, alpha, rcpa, s_gb, s_pv); \
    r0.z = lcq_core(V0.z, alpha, rcpa, s_gb, s_pv); \
    r0.w = lcq_core(V0.w, alpha, rcpa, s_gb, s_pv); \
    r1.x = lcq_core(V1.x, alpha, rcpa, s_gb, s_pv); \
    r1.y = lcq_core(V1.y, alpha, rcpa, s_gb, s_pv); \
    r1.z = lcq_core(V1.z, alpha, rcpa, s_gb, s_pv); \
    r1.w = lcq_core(V1.w, alpha, rcpa, s_gb, s_pv); \
    r2.x = lcq_core(V2.x, alpha, rcpa, s_gb, s_pv); \
    r2.y = lcq_core(V2.y, alpha, rcpa, s_gb, s_pv); \
    r2.z = lcq_core(V2.z, alpha, rcpa, s_gb, s_pv); \
    r2.w = lcq_core(V2.w, alpha, rcpa, s_gb, s_pv); \
    r3.x = lcq_core(V3.x, alpha, rcpa, s_gb, s_pv); \
    r3.y = lcq_core(V3.y, alpha, rcpa, s_gb, s_pv); \
    r3.z = lcq_core(V3.z, alpha, rcpa, s_gb, s_pv); \
    r3.w = lcq_core(V3.w, alpha, rcpa, s_gb, s_pv); \
    __builtin_nontemporal_store(r0, (vf4*)&o4[blk + (off)]); \
    __builtin_nontemporal_store(r1, (vf4*)&o4[blk + (off) + 256u]); \
    __builtin_nontemporal_store(r2, (vf4*)&o4[blk + (off) + 512u]); \
    __builtin_nontemporal_store(r3, (vf4*)&o4[blk + (off) + 768u]); }

    if ((long long)(blockIdx.x + 1) * 4096ll <= n4ll) {
        // Full fast path (bench shape: 8,388,608 float4 = 2048 exact blocks).
        // Depth-1 register pipeline: while chunk i computes, chunk i+1's 4
        // loads are in flight (compiler emits partial vmcnt waits).
        vf4 a0, a1, a2, a3;   // ping
        vf4 b0, b1, b2, b3;   // pong
        LCQ_LOAD(a0, a1, a2, a3, 0u)
        LCQ_LOAD(b0, b1, b2, b3, 1024u)
        LCQ_CS(a0, a1, a2, a3, 0u)        // waits only on a*, b* stays in flight
        LCQ_LOAD(a0, a1, a2, a3, 2048u)   // refill ping while pong computes
        LCQ_CS(b0, b1, b2, b3, 1024u)
        LCQ_LOAD(b0, b1, b2, b3, 3072u)
        LCQ_CS(a0, a1, a2, a3, 2048u)
        LCQ_CS(b0, b1, b2, b3, 3072u)
    } else {
        // Partial block (not hit at bench shape; kept for generality).
        #pragma unroll 1
        for (int c = 0; c < 4; ++c) {
            #pragma unroll
            for (int k = 0; k < 4; ++k) {
                long long i = (long long)blk + c * 1024 + k * 256;
                if (i < n4ll) {
                    vf4 v = x4[i];
                    vf4 r;
                    r.x = lcq_core(v.x, alpha, rcpa, s_gb, s_pv);
                    r.y = lcq_core(v.y, alpha, rcpa, s_gb, s_pv);
                    r.z = lcq_core(v.z, alpha, rcpa, s_gb, s_pv);
                    r.w = lcq_core(v.w, alpha, rcpa, s_gb, s_pv);
                    o4[i] = r;
                }
            }
        }
        // scalar remainder (n % 4), handled by the last block only
        if (blockIdx.x == gridDim.x - 1) {
            for (long long k = (n4ll << 2) + threadIdx.x; k < n; k += 256) {
                out[k] = lcq_core(x[k], alpha, rcpa, s_gb, s_pv);
            }
        }
    }
#undef LCQ_LOAD
#undef LCQ_CS
}

extern "C" void kernel_launch(void* const* d_in, const int* in_sizes, int n_in,
                              void* d_out, int out_size, void* d_ws, size_t ws_size,
                              hipStream_t stream) {
    const float* x     = (const float*)d_in[0];   // (4,4096,2048) fp32
    const float* thr   = (const float*)d_in[1];   // (1,) alpha
    const float* theta = (const float*)d_in[2];   // (16,)
    float* out = (float*)d_out;

    long long n = (long long)in_sizes[0];
    long long n4 = n >> 2;
    long long chunks = (n4 + 1023) / 1024;
    long long grid = (chunks + 3) / 4;            // bench: 2048 blocks x 256KB
    if (grid < 1) grid = 1;
    dim3 block(256);
    hipLaunchKernelGGL(lcq_kernel, dim3((unsigned)grid), block, 0, stream,
                       x, thr, theta, out, n);
}

// Round 5
// 237.409 us; speedup vs baseline: 1.0691x; 1.0691x over previous
//
#include <hip/hip_runtime.h>
#include <math.h>

#define KB 16

// Native clang vector type — required for __builtin_nontemporal_load/store.
typedef float vf4 __attribute__((ext_vector_type(4)));

// Per-element core. Faithful fp32 op order vs reference (__f*_rn blocks FMA
// contraction; rintf == round-half-even == jnp.round). Division by alpha is
// multiply by precomputed 1/alpha — bit-exact for pow2 alpha (bench: 1.0).
// Table holds pv[m] = __fmul_rn(alpha, zval[m]) — same operands/op as the
// reference's final alpha-multiply -> bit-identical (R4: absmax 0.0 with this
// fold); high path alpha*1.0 == alpha exactly.
__device__ __forceinline__ float lcq_core(float xv, float alpha, float rcp_alpha,
                                          const float2* __restrict__ s_gb,
                                          const float* __restrict__ s_pv)
{
    float a   = fabsf(xv);
    float xt  = __fmul_rn(a, rcp_alpha);            // x_tmp = |x|/alpha
    float t16 = __fmul_rn(xt, 16.0f);               // exact pow2 scale
    float jf  = fminf(t16, 15.0f);
    int   j   = (int)jf;                            // searchsorted(dst,·,right)-1
    float2 gb = s_gb[j];                            // ds_read_b64, conflict-free
    float dj  = __fmul_rn(floorf(jf), 0.0625f);     // dst[j] = j/16, exact
    float y   = __fadd_rn(__fmul_rn(gb.x, __fsub_rn(xt, dj)), gb.y);
    float t   = rintf(__fmul_rn(y, 15.0f));         // m = round(y*s), half-even; t>=0
    int   m   = (int)fminf(t, 15.0f);
    float r   = (a < alpha) ? s_pv[m] : alpha;      // flag select, alpha pre-folded
    return copysignf(r, xv);                        // x==0 -> 0 (pv[0]==0)
}

// Geometry: EXACT revert to the 236us baseline — 8192 one-shot blocks, each
// owns float4 indices [b*1024,(b+1)*1024) (64KB), 4 NT loads -> 16 elems ->
// 4 NT stores, retire. (R2: plain ld/st = +12us; R4: 256KB pipelined blocks
// = +20us. Block churn + NT both load-bearing.)
//
// ROUND 5 single change: the 4 input loads are issued BEFORE table setup.
// Previously every block ran ~1200cy of single-lane setup (16 expf, 17 fdiv,
// 16x16 zval loop) with all 4 waves parked, and only then issued loads
// (~900cy HBM latency) — latencies ADDED. Now load issue happens at t=0 and
// the HBM latency hides under setup; the compiler-emitted vmcnt(0) drain at
// __syncthreads lands after the loads have already arrived. (This also
// explains R1's null: hoisted-table variant still serialized table-load ->
// barrier -> input loads.)
__global__ __launch_bounds__(256) void lcq_kernel(
    const float* __restrict__ x,
    const float* __restrict__ thr,
    const float* __restrict__ theta,
    float* __restrict__ out,
    long long n)
{
    __shared__ float2 s_gb[KB];     // (gamma[j], beta[j])
    __shared__ float  s_pv[KB];     // alpha * expand(m/15)
    __shared__ float  s_scal[2];    // alpha, 1/alpha

    const long long n4ll = n >> 2;
    const vf4* __restrict__ x4 = (const vf4*)x;
    vf4* __restrict__ o4 = (vf4*)out;

    const unsigned base = blockIdx.x * 1024u + threadIdx.x;  // float4 index
    const bool full = ((long long)(blockIdx.x + 1) * 1024ll <= n4ll);

    // ---- (1) issue input loads first (independent of tables) ----
    vf4 v0, v1, v2, v3;
    if (full) {
        v0 = __builtin_nontemporal_load(&x4[base]);
        v1 = __builtin_nontemporal_load(&x4[base + 256u]);
        v2 = __builtin_nontemporal_load(&x4[base + 512u]);
        v3 = __builtin_nontemporal_load(&x4[base + 768u]);
    }

    // ---- (2) table setup overlaps the load latency ----
    if (threadIdx.x == 0) {
        // softmax(theta), fp32, sequential order (bit-matched all rounds)
        float th[KB];
        float mx = theta[0];
        th[0] = mx;
        #pragma unroll
        for (int i = 1; i < KB; ++i) { th[i] = theta[i]; mx = fmaxf(mx, th[i]); }
        float ex[KB];
        float sum = 0.0f;
        #pragma unroll
        for (int i = 0; i < KB; ++i) { ex[i] = expf(__fsub_rn(th[i], mx)); sum = __fadd_rn(sum, ex[i]); }
        float sm[KB];
        #pragma unroll
        for (int i = 0; i < KB; ++i) sm[i] = __fdiv_rn(ex[i], sum);

        float beta[KB], gamma[KB];
        beta[0] = 0.0f;
        float c = sm[0];
        #pragma unroll
        for (int i = 1; i < KB; ++i) { beta[i] = c; c = __fadd_rn(c, sm[i]); }
        #pragma unroll
        for (int i = 0; i < KB; ++i) gamma[i] = __fmul_rn(sm[i], 16.0f);

        #pragma unroll
        for (int i = 0; i < KB; ++i) s_gb[i] = make_float2(gamma[i], beta[i]);

        float alpha = thr[0];
        s_scal[0] = alpha;
        s_scal[1] = __fdiv_rn(1.0f, alpha);  // exact for pow2 alpha (bench: 1.0)

        // pv[m] = alpha * expand(m/15): searchsorted + inverse affine, then
        // the reference's alpha-multiply pre-folded (same operands -> same bits)
        for (int m = 0; m < KB; ++m) {
            float yq = __fdiv_rn((float)m, 15.0f);
            int iq = 0;
            #pragma unroll
            for (int i = 1; i < KB; ++i) iq += (beta[i] <= yq) ? 1 : 0;
            float zv = __fadd_rn(__fdiv_rn(__fsub_rn(yq, beta[iq]), gamma[iq]),
                                 (float)iq * 0.0625f);
            s_pv[m] = __fmul_rn(alpha, zv);
        }
    }
    __syncthreads();   // vmcnt/lgkm drain — loads issued ~1200cy ago have landed

    const float alpha = s_scal[0];
    const float rcpa  = s_scal[1];

    // ---- (3) compute + NT stores ----
    if (full) {
        vf4 r0, r1, r2, r3;
        r0.x = lcq_core(v0.x, alpha, rcpa, s_gb, s_pv);
        r0.y = lcq_core(v0.y, alpha, rcpa, s_gb, s_pv);
        r0.z = lcq_core(v0.z, alpha, rcpa, s_gb, s_pv);
        r0.w = lcq_core(v0.w, alpha, rcpa, s_gb, s_pv);
        r1.x = lcq_core(v1.x, alpha, rcpa, s_gb, s_pv);
        r1.y = lcq_core(v1.y, alpha, rcpa, s_gb, s_pv);
        r1.z = lcq_core(v1.z, alpha, rcpa, s_gb, s_pv);
        r1.w = lcq_core(v1.w, alpha, rcpa, s_gb, s_pv);
        r2.x = lcq_core(v2.x, alpha, rcpa, s_gb, s_pv);
        r2.y = lcq_core(v2.y, alpha, rcpa, s_gb, s_pv);
        r2.z = lcq_core(v2.z, alpha, rcpa, s_gb, s_pv);
        r2.w = lcq_core(v2.w, alpha, rcpa, s_gb, s_pv);
        r3.x = lcq_core(v3.x, alpha, rcpa, s_gb, s_pv);
        r3.y = lcq_core(v3.y, alpha, rcpa, s_gb, s_pv);
        r3.z = lcq_core(v3.z, alpha, rcpa, s_gb, s_pv);
        r3.w = lcq_core(v3.w, alpha, rcpa, s_gb, s_pv);
        __builtin_nontemporal_store(r0, &o4[base]);
        __builtin_nontemporal_store(r1, &o4[base + 256u]);
        __builtin_nontemporal_store(r2, &o4[base + 512u]);
        __builtin_nontemporal_store(r3, &o4[base + 768u]);
    } else {
        // Partial last block (not hit at bench shape; kept for generality).
        #pragma unroll
        for (int k = 0; k < 4; ++k) {
            long long i = (long long)base + k * 256;
            if (i < n4ll) {
                vf4 v = x4[i];
                vf4 r;
                r.x = lcq_core(v.x, alpha, rcpa, s_gb, s_pv);
                r.y = lcq_core(v.y, alpha, rcpa, s_gb, s_pv);
                r.z = lcq_core(v.z, alpha, rcpa, s_gb, s_pv);
                r.w = lcq_core(v.w, alpha, rcpa, s_gb, s_pv);
                o4[i] = r;
            }
        }
        // scalar remainder (n % 4), handled by the last block only
        if (blockIdx.x == gridDim.x - 1) {
            for (long long k = (n4ll << 2) + threadIdx.x; k < n; k += 256) {
                out[k] = lcq_core(x[k], alpha, rcpa, s_gb, s_pv);
            }
        }
    }
}

extern "C" void kernel_launch(void* const* d_in, const int* in_sizes, int n_in,
                              void* d_out, int out_size, void* d_ws, size_t ws_size,
                              hipStream_t stream) {
    const float* x     = (const float*)d_in[0];   // (4,4096,2048) fp32
    const float* thr   = (const float*)d_in[1];   // (1,) alpha
    const float* theta = (const float*)d_in[2];   // (16,)
    float* out = (float*)d_out;

    long long n = (long long)in_sizes[0];
    long long n4 = n >> 2;
    long long grid = (n4 + 1023) / 1024;          // bench: 8192 one-shot blocks
    if (grid < 1) grid = 1;
    dim3 block(256);
    hipLaunchKernelGGL(lcq_kernel, dim3((unsigned)grid), block, 0, stream,
                       x, thr, theta, out, n);
}